// Round 7
// baseline (468.950 us; speedup 1.0000x reference)
//
#include <hip/hip_runtime.h>
#include <math.h>

typedef unsigned short u16;
typedef unsigned int u32;

#define CAP 64            // max in-degree stored per node (Poisson(16): P(>64) ~ 1e-20)
#define CHUNK 1024        // edges per work-stealing ticket

// bf16 <-> f32 (bf16 = truncated f32; up-convert is an exact shift)
__device__ inline float bf2f(u16 u) {
    union { u32 i; float f; } c; c.i = ((u32)u) << 16; return c.f;
}
__device__ inline u16 f2bf(float f) {  // round-to-nearest-even
    union { float f; u32 i; } c; c.f = f;
    u32 r = c.i + 0x7FFFu + ((c.i >> 16) & 1u);
    return (u16)(r >> 16);
}

// ---------------- adjacency build (fixed-capacity 2D, XCD-affine) ----------------

__global__ void zero_kernel(int* __restrict__ cnt, int* __restrict__ tickets, int n) {
    int i = blockIdx.x * blockDim.x + threadIdx.x;
    if (i < n) cnt[i] = 0;
    if (i < 8 * 16) tickets[i] = 0;
}

// One pass builds the whole adjacency: k = atomicAdd(cnt[d]), srcs2d[d*64+k] = src.
// dst space is split into 8 ranges; waves drain per-range chunk tickets, preferring
// the range matching their physical XCD (XCC_ID hwreg) so cnt/srcs2d lines are
// touched by a single XCD's L2 (round-6 post-mortem: cross-XCD atomic line
// migration wrote 50 MB for a 400 KB array). Ticket stealing guarantees coverage
// for ANY block->XCD mapping; affinity is a perf heuristic only.
__global__ void fill2d_kernel(const int* __restrict__ src, const int* __restrict__ dst,
                              int* __restrict__ cnt, int* __restrict__ srcs2d,
                              int* __restrict__ tickets, int e, int n) {
    int xcc;
    asm volatile("s_getreg_b32 %0, hwreg(20, 0, 32)" : "=s"(xcc));  // 20 = HW_REG_XCC_ID (gfx940+)
    xcc &= 7;
    int lane = threadIdx.x & 63;
    int nchunk = (e + CHUNK - 1) / CHUNK;
    for (int rr = 0; rr < 8; ++rr) {
        int r = (xcc + rr) & 7;
        int lo = (int)(((long long)n * r) >> 3);
        int hi = (int)(((long long)n * (r + 1)) >> 3);
        while (true) {
            int t = 0;
            if (lane == 0) t = atomicAdd(&tickets[r * 16], 1);   // 64B-strided tickets
            t = __builtin_amdgcn_readfirstlane(__shfl(t, 0));
            if (t >= nchunk) break;
            int i0 = t * CHUNK;
            int i1 = i0 + CHUNK; if (i1 > e) i1 = e;
            for (int i = i0 + lane; i < i1; i += 64) {
                int d = dst[i];
                if (d >= lo && d < hi) {
                    int k = atomicAdd(&cnt[d], 1);
                    if (k < CAP) srcs2d[((size_t)d << 6) + k] = src[i];
                }
            }
        }
    }
}

// dis[i] = rsqrt(deg_in + 1)   (self-loop included)
__global__ void dis_kernel(const int* __restrict__ cnt, float* __restrict__ dis, int n) {
    int i = blockIdx.x * blockDim.x + threadIdx.x;
    if (i < n) dis[i] = rsqrtf((float)cnt[i] + 1.0f);
}

// ---------------- register-tiled GEMM: Y[n,OUT] = X[n,IN] @ W[IN,OUT] (+bias) ----------------
// block = 256 threads -> 64 rows x 64 (padded) cols; thread = 4x4 tile.
// k-loop kept at unroll 1 (round-3 post-mortem: full unroll -> 256 VGPR spill).

__device__ inline float4 load4(const float* p) { return *(const float4*)p; }
__device__ inline float4 load4(const u16* p) {
    ushort4 u = *(const ushort4*)p;
    return make_float4(bf2f(u.x), bf2f(u.y), bf2f(u.z), bf2f(u.w));
}

template<typename XT, typename YT, int IN_F, int OUT_F, bool BIAS>
__global__ __launch_bounds__(256) void gemm_tile_kernel(const XT* __restrict__ X,
                                                        const float* __restrict__ W,
                                                        const float* __restrict__ bias,
                                                        YT* __restrict__ Y, int n) {
    constexpr int PC = 64;  // padded col count
    __shared__ float Wl[IN_F * PC];
    int tid = threadIdx.x;
    for (int idx = tid; idx < IN_F * PC; idx += 256) {
        int k = idx / PC, c = idx % PC;
        Wl[idx] = (c < OUT_F) ? W[k * OUT_F + c] : 0.f;
    }
    __syncthreads();
    int tx = tid & 15;   // col group (4 cols)
    int ty = tid >> 4;   // row group (4 rows)
    int r0 = blockIdx.x * 64 + ty * 4;
    int c0 = tx * 4;
    // clamped row pointers: always in-bounds, no per-iteration select
    const XT* xr[4];
    #pragma unroll
    for (int i = 0; i < 4; ++i) {
        int r = r0 + i;
        if (r >= n) r = n - 1;
        xr[i] = X + (size_t)r * IN_F;
    }
    float acc[4][4] = {};
    const float4* Wv = (const float4*)Wl;  // index: k*16 + tx
    #pragma unroll 1
    for (int k = 0; k < IN_F; k += 4) {
        float4 xv[4];
        #pragma unroll
        for (int i = 0; i < 4; ++i) xv[i] = load4(xr[i] + k);
        #pragma unroll
        for (int j = 0; j < 4; ++j) {
            float4 wv = Wv[(k + j) * 16 + tx];
            #pragma unroll
            for (int i = 0; i < 4; ++i) {
                float xs = (j == 0) ? xv[i].x : (j == 1) ? xv[i].y : (j == 2) ? xv[i].z : xv[i].w;
                acc[i][0] = fmaf(xs, wv.x, acc[i][0]);
                acc[i][1] = fmaf(xs, wv.y, acc[i][1]);
                acc[i][2] = fmaf(xs, wv.z, acc[i][2]);
                acc[i][3] = fmaf(xs, wv.w, acc[i][3]);
            }
        }
    }
    if (c0 < OUT_F) {
        float4 bb = make_float4(0.f, 0.f, 0.f, 0.f);
        if (BIAS) bb = *(const float4*)(bias + c0);
        #pragma unroll
        for (int i = 0; i < 4; ++i) {
            int r = r0 + i;
            if (r < n) {
                if constexpr (sizeof(YT) == 2) {
                    ushort4 o;
                    o.x = f2bf(acc[i][0] + bb.x);
                    o.y = f2bf(acc[i][1] + bb.y);
                    o.z = f2bf(acc[i][2] + bb.z);
                    o.w = f2bf(acc[i][3] + bb.w);
                    *(ushort4*)(Y + (size_t)r * OUT_F + c0) = o;
                } else {
                    float4 o = make_float4(acc[i][0] + bb.x, acc[i][1] + bb.y,
                                           acc[i][2] + bb.z, acc[i][3] + bb.w);
                    *(float4*)(Y + (size_t)r * OUT_F + c0) = o;
                }
            }
        }
    }
}

// ---------------- gather aggregation (one 64-lane wave per node, 64 bf16 cols) ----------------
// out[i,c] = act( dis_i^2 * v[i,c] + sum_k dis[s_k]*dis_i * v[s_k, c]  (+ b[c]) )
// unroll 8 for memory-level parallelism on the random 128B row gathers.

template<bool RELU_BIAS>
__global__ void gather64_kernel(const u16* __restrict__ v, const int* __restrict__ cnt,
                                const int* __restrict__ srcs2d, const float* __restrict__ dis,
                                const float* __restrict__ b, u16* __restrict__ out, int n) {
    int wid = __builtin_amdgcn_readfirstlane((blockIdx.x * blockDim.x + threadIdx.x) >> 6);
    int lane = threadIdx.x & 63;
    if (wid >= n) return;  // wave-uniform
    int deg = __builtin_amdgcn_readfirstlane(cnt[wid]);
    if (deg > CAP) deg = CAP;
    const int* sp = srcs2d + ((size_t)wid << 6);
    float di = dis[wid];
    float acc = bf2f(v[((size_t)wid << 6) + lane]) * (di * di);
    int k = 0;
    for (; k + 8 <= deg; k += 8) {
        int s[8];
        #pragma unroll
        for (int q = 0; q < 8; ++q) s[q] = sp[k + q];
        float w[8];
        #pragma unroll
        for (int q = 0; q < 8; ++q) w[q] = dis[s[q]];
        float vv[8];
        #pragma unroll
        for (int q = 0; q < 8; ++q) vv[q] = bf2f(v[((size_t)s[q] << 6) + lane]);
        #pragma unroll
        for (int q = 0; q < 8; ++q) acc = fmaf(vv[q], w[q] * di, acc);
    }
    for (; k < deg; ++k) {
        int s = sp[k];
        acc = fmaf(bf2f(v[((size_t)s << 6) + lane]), dis[s] * di, acc);
    }
    if (RELU_BIAS) acc = fmaxf(acc + b[lane], 0.f);
    out[((size_t)wid << 6) + lane] = f2bf(acc);
}

// in-place log_softmax over 40 cols; one wave per row
__global__ void logsoftmax_kernel(float* __restrict__ z, int n) {
    int wid = (blockIdx.x * blockDim.x + threadIdx.x) >> 6;
    int lane = threadIdx.x & 63;
    if (wid >= n) return;
    float zz = (lane < 40) ? z[(size_t)wid * 40 + lane] : -INFINITY;
    float v = zz;
    #pragma unroll
    for (int off = 32; off > 0; off >>= 1) v = fmaxf(v, __shfl_xor(v, off));
    float ex = (lane < 40) ? expf(zz - v) : 0.f;
    float s = ex;
    #pragma unroll
    for (int off = 32; off > 0; off >>= 1) s += __shfl_xor(s, off);
    float ls = logf(s);
    if (lane < 40) z[(size_t)wid * 40 + lane] = zz - v - ls;
}

// ---------------- launch ----------------

extern "C" void kernel_launch(void* const* d_in, const int* in_sizes, int n_in,
                              void* d_out, int out_size, void* d_ws, size_t ws_size,
                              hipStream_t stream) {
    const float* x  = (const float*)d_in[0];
    const int*   ei = (const int*)d_in[1];   // [2, E] int32
    const float* W1 = (const float*)d_in[2]; // [128, 64]
    const float* b1 = (const float*)d_in[3]; // [64]
    const float* W2 = (const float*)d_in[4]; // [64, 40]
    const float* b2 = (const float*)d_in[5]; // [40]
    float* out = (float*)d_out;              // [n, 40]

    const int n = in_sizes[0] / 128;
    const int e = in_sizes[1] / 2;
    const int* src = ei;
    const int* dst = ei + e;

    // workspace layout:
    //   cnt[n] i32 | tickets[128] i32 | dis[n] f32 | srcs2d[n*64] i32 |
    //   A[n*64] bf16 | B[n*64] bf16                          (~52 MB)
    int* cnt     = (int*)d_ws;
    int* tickets = cnt + n;
    float* dis   = (float*)(tickets + 128);
    int* srcs2d  = (int*)(dis + n);
    u16* A       = (u16*)(srcs2d + ((size_t)n << 6));  // xw1 (bf16), then G
    u16* B       = A + ((size_t)n << 6);               // H (bf16)

    const int T = 256;

    // --- adjacency build + normalization ---
    zero_kernel<<<(n + T - 1) / T, T, 0, stream>>>(cnt, tickets, n);
    fill2d_kernel<<<1024, T, 0, stream>>>(src, dst, cnt, srcs2d, tickets, e, n);
    dis_kernel<<<(n + T - 1) / T, T, 0, stream>>>(cnt, dis, n);

    // --- layer 1: xw1 = x@W1 (bf16) ; H = relu(aggregate(xw1) + b1) (bf16) ---
    gemm_tile_kernel<float, u16, 128, 64, false>
        <<<(n + 63) / 64, 256, 0, stream>>>(x, W1, nullptr, A, n);
    gather64_kernel<true><<<(n * 64 + T - 1) / T, T, 0, stream>>>(A, cnt, srcs2d, dis, b1, B, n);

    // --- layer 2 (reassociated): G = aggregate(H) (bf16); out = log_softmax(G@W2 + b2) ---
    gather64_kernel<false><<<(n * 64 + T - 1) / T, T, 0, stream>>>(B, cnt, srcs2d, dis, nullptr, A, n);
    gemm_tile_kernel<u16, float, 64, 40, true>
        <<<(n + 63) / 64, 256, 0, stream>>>(A, W2, b2, out, n);
    logsoftmax_kernel<<<(n * 64 + T - 1) / T, T, 0, stream>>>(out, n);
}

// Round 8
// 366.598 us; speedup vs baseline: 1.2792x; 1.2792x over previous
//
#include <hip/hip_runtime.h>
#include <math.h>

typedef unsigned short u16;
typedef unsigned int u32;

#define CAP 64      // max in-degree stored per node (Poisson(16): P(>64) ~ 1e-20)
#define BSHIFT 9    // 512 nodes per bucket -> nb = ceil(n/512) <= 256 for n <= 131072
#define BCAP 9600   // records per bucket region (mean 8163, sigma ~90 -> 16 sigma headroom)

// bf16 <-> f32 (bf16 = truncated f32; up-convert is an exact shift)
__device__ inline float bf2f(u16 u) {
    union { u32 i; float f; } c; c.i = ((u32)u) << 16; return c.f;
}
__device__ inline u16 f2bf(float f) {  // round-to-nearest-even
    union { float f; u32 i; } c; c.f = f;
    u32 r = c.i + 0x7FFFu + ((c.i >> 16) & 1u);
    return (u16)(r >> 16);
}

// ---------------- adjacency build: two-pass LDS bucket sort ----------------
// Round-7 post-mortem: device-scope atomics execute at the memory-side coherence
// point (XCD-affinity didn't reduce the 80 MB write traffic), so the fix is to
// eliminate per-edge random global atomics entirely.

__global__ void zero_gcount_kernel(int* __restrict__ gcount) {
    gcount[threadIdx.x] = 0;
}

// Pass 1: per-block LDS histogram over buckets, one global atomic PER (block,bucket)
// to reserve space, then LDS-cursor scatter -> each block writes each bucket a
// contiguous ~18-record run (dense lines, minimal amplification).
__global__ __launch_bounds__(256) void bucket_kernel(const int* __restrict__ src,
                                                     const int* __restrict__ dst,
                                                     int* __restrict__ gcount,
                                                     int2* __restrict__ bucketbuf,
                                                     int e, int nb) {
    __shared__ int lh[256];
    int tid = threadIdx.x;
    if (tid < nb) lh[tid] = 0;
    __syncthreads();
    int per = (e + gridDim.x - 1) / gridDim.x;
    int i0 = blockIdx.x * per;
    int i1 = i0 + per; if (i1 > e) i1 = e;
    for (int i = i0 + tid; i < i1; i += 256)
        atomicAdd(&lh[dst[i] >> BSHIFT], 1);
    __syncthreads();
    if (tid < nb) {
        int c = lh[tid];
        lh[tid] = (c > 0) ? atomicAdd(&gcount[tid], c) : 0;
    }
    __syncthreads();
    for (int i = i0 + tid; i < i1; i += 256) {
        int d = dst[i], s = src[i];
        int b = d >> BSHIFT;
        int pos = atomicAdd(&lh[b], 1);  // LDS cursor -> unique global slot
        if (pos < BCAP) bucketbuf[(size_t)b * BCAP + pos] = make_int2(d, s);
    }
}

// Pass 2: one block per bucket. LDS per-node counts (LDS atomics), direct writes
// into the bucket's 128 KB srcs2d window (L2-resident -> merging write-back).
// Degrees + dis fused.
__global__ __launch_bounds__(256) void csrify_kernel(const int2* __restrict__ bucketbuf,
                                                     const int* __restrict__ gcount,
                                                     int* __restrict__ cnt,
                                                     float* __restrict__ dis,
                                                     int* __restrict__ srcs2d, int n) {
    __shared__ int lc[512];
    int b = blockIdx.x;
    int tid = threadIdx.x;
    int node_lo = b << BSHIFT;
    #pragma unroll
    for (int q = tid; q < 512; q += 256) lc[q] = 0;
    __syncthreads();
    int m = gcount[b]; if (m > BCAP) m = BCAP;
    const int2* bp = bucketbuf + (size_t)b * BCAP;
    for (int i = tid; i < m; i += 256) {
        int2 r = bp[i];
        int k = atomicAdd(&lc[r.x - node_lo], 1);
        if (k < CAP) srcs2d[((size_t)r.x << 6) + k] = r.y;
    }
    __syncthreads();
    for (int q = tid; q < 512; q += 256) {
        int node = node_lo + q;
        if (node < n) {
            int c = lc[q];
            cnt[node] = c;
            dis[node] = rsqrtf((float)c + 1.0f);
        }
    }
}

// ---------------- register-tiled GEMM: Y[n,OUT] = X[n,IN] @ W[IN,OUT] (+bias) ----------------
// block = 256 threads -> 64 rows x 64 (padded) cols; thread = 4x4 tile.
// k-loop kept at unroll 1 (round-3 post-mortem: full unroll -> 256 VGPR spill).

__device__ inline float4 load4(const float* p) { return *(const float4*)p; }
__device__ inline float4 load4(const u16* p) {
    ushort4 u = *(const ushort4*)p;
    return make_float4(bf2f(u.x), bf2f(u.y), bf2f(u.z), bf2f(u.w));
}

template<typename XT, typename YT, int IN_F, int OUT_F, bool BIAS>
__global__ __launch_bounds__(256) void gemm_tile_kernel(const XT* __restrict__ X,
                                                        const float* __restrict__ W,
                                                        const float* __restrict__ bias,
                                                        YT* __restrict__ Y, int n) {
    constexpr int PC = 64;  // padded col count
    __shared__ float Wl[IN_F * PC];
    int tid = threadIdx.x;
    for (int idx = tid; idx < IN_F * PC; idx += 256) {
        int k = idx / PC, c = idx % PC;
        Wl[idx] = (c < OUT_F) ? W[k * OUT_F + c] : 0.f;
    }
    __syncthreads();
    int tx = tid & 15;   // col group (4 cols)
    int ty = tid >> 4;   // row group (4 rows)
    int r0 = blockIdx.x * 64 + ty * 4;
    int c0 = tx * 4;
    // clamped row pointers: always in-bounds, no per-iteration select
    const XT* xr[4];
    #pragma unroll
    for (int i = 0; i < 4; ++i) {
        int r = r0 + i;
        if (r >= n) r = n - 1;
        xr[i] = X + (size_t)r * IN_F;
    }
    float acc[4][4] = {};
    const float4* Wv = (const float4*)Wl;  // index: k*16 + tx
    #pragma unroll 1
    for (int k = 0; k < IN_F; k += 4) {
        float4 xv[4];
        #pragma unroll
        for (int i = 0; i < 4; ++i) xv[i] = load4(xr[i] + k);
        #pragma unroll
        for (int j = 0; j < 4; ++j) {
            float4 wv = Wv[(k + j) * 16 + tx];
            #pragma unroll
            for (int i = 0; i < 4; ++i) {
                float xs = (j == 0) ? xv[i].x : (j == 1) ? xv[i].y : (j == 2) ? xv[i].z : xv[i].w;
                acc[i][0] = fmaf(xs, wv.x, acc[i][0]);
                acc[i][1] = fmaf(xs, wv.y, acc[i][1]);
                acc[i][2] = fmaf(xs, wv.z, acc[i][2]);
                acc[i][3] = fmaf(xs, wv.w, acc[i][3]);
            }
        }
    }
    if (c0 < OUT_F) {
        float4 bb = make_float4(0.f, 0.f, 0.f, 0.f);
        if (BIAS) bb = *(const float4*)(bias + c0);
        #pragma unroll
        for (int i = 0; i < 4; ++i) {
            int r = r0 + i;
            if (r < n) {
                if constexpr (sizeof(YT) == 2) {
                    ushort4 o;
                    o.x = f2bf(acc[i][0] + bb.x);
                    o.y = f2bf(acc[i][1] + bb.y);
                    o.z = f2bf(acc[i][2] + bb.z);
                    o.w = f2bf(acc[i][3] + bb.w);
                    *(ushort4*)(Y + (size_t)r * OUT_F + c0) = o;
                } else {
                    float4 o = make_float4(acc[i][0] + bb.x, acc[i][1] + bb.y,
                                           acc[i][2] + bb.z, acc[i][3] + bb.w);
                    *(float4*)(Y + (size_t)r * OUT_F + c0) = o;
                }
            }
        }
    }
}

// ---------------- gather aggregation (one 64-lane wave per node, 64 bf16 cols) ----------------
// out[i,c] = relu( dis_i^2 * v[i,c] + sum_k dis[s_k]*dis_i * v[s_k, c] + b[c] )

__global__ void gather64_kernel(const u16* __restrict__ v, const int* __restrict__ cnt,
                                const int* __restrict__ srcs2d, const float* __restrict__ dis,
                                const float* __restrict__ b, u16* __restrict__ out, int n) {
    int wid = __builtin_amdgcn_readfirstlane((blockIdx.x * blockDim.x + threadIdx.x) >> 6);
    int lane = threadIdx.x & 63;
    if (wid >= n) return;  // wave-uniform
    int deg = __builtin_amdgcn_readfirstlane(cnt[wid]);
    if (deg > CAP) deg = CAP;
    const int* sp = srcs2d + ((size_t)wid << 6);
    float di = dis[wid];
    float acc = bf2f(v[((size_t)wid << 6) + lane]) * (di * di);
    int k = 0;
    for (; k + 8 <= deg; k += 8) {
        int s[8];
        #pragma unroll
        for (int q = 0; q < 8; ++q) s[q] = sp[k + q];
        float w[8];
        #pragma unroll
        for (int q = 0; q < 8; ++q) w[q] = dis[s[q]];
        float vv[8];
        #pragma unroll
        for (int q = 0; q < 8; ++q) vv[q] = bf2f(v[((size_t)s[q] << 6) + lane]);
        #pragma unroll
        for (int q = 0; q < 8; ++q) acc = fmaf(vv[q], w[q] * di, acc);
    }
    for (; k < deg; ++k) {
        int s = sp[k];
        acc = fmaf(bf2f(v[((size_t)s << 6) + lane]), dis[s] * di, acc);
    }
    acc = fmaxf(acc + b[lane], 0.f);
    out[((size_t)wid << 6) + lane] = f2bf(acc);
}

// ---------------- 40-col gather + bias + log_softmax (one wave per node) ----------------
// out[i,:] = log_softmax( dis_i^2*z[i,:] + sum_k dis[s_k]*dis_i*z[s_k,:] + b2 )
// z rows are 40 bf16 = 80 B -> 38% less gather read traffic than 64-col layout.

__global__ void gather40_kernel(const u16* __restrict__ z, const int* __restrict__ cnt,
                                const int* __restrict__ srcs2d, const float* __restrict__ dis,
                                const float* __restrict__ b2, float* __restrict__ out, int n) {
    int wid = __builtin_amdgcn_readfirstlane((blockIdx.x * blockDim.x + threadIdx.x) >> 6);
    int lane = threadIdx.x & 63;
    if (wid >= n) return;  // wave-uniform
    int deg = __builtin_amdgcn_readfirstlane(cnt[wid]);
    if (deg > CAP) deg = CAP;
    const int* sp = srcs2d + ((size_t)wid << 6);
    float di = dis[wid];
    bool act = lane < 40;
    float acc = act ? bf2f(z[(size_t)wid * 40 + lane]) * (di * di) : 0.f;
    int k = 0;
    for (; k + 8 <= deg; k += 8) {
        int s[8];
        #pragma unroll
        for (int q = 0; q < 8; ++q) s[q] = sp[k + q];
        float w[8];
        #pragma unroll
        for (int q = 0; q < 8; ++q) w[q] = dis[s[q]];
        float vv[8];
        #pragma unroll
        for (int q = 0; q < 8; ++q) vv[q] = act ? bf2f(z[(size_t)s[q] * 40 + lane]) : 0.f;
        #pragma unroll
        for (int q = 0; q < 8; ++q) acc = fmaf(vv[q], w[q] * di, acc);
    }
    for (; k < deg; ++k) {
        int s = sp[k];
        if (act) acc = fmaf(bf2f(z[(size_t)s * 40 + lane]), dis[s] * di, acc);
    }
    // fused bias + log_softmax over lanes 0..39
    float zz = act ? acc + b2[lane] : -INFINITY;
    float v = zz;
    #pragma unroll
    for (int off = 32; off > 0; off >>= 1) v = fmaxf(v, __shfl_xor(v, off));
    float ex = act ? expf(zz - v) : 0.f;
    float ss = ex;
    #pragma unroll
    for (int off = 32; off > 0; off >>= 1) ss += __shfl_xor(ss, off);
    float ls = logf(ss);
    if (act) out[(size_t)wid * 40 + lane] = zz - v - ls;
}

// ---------------- launch ----------------

extern "C" void kernel_launch(void* const* d_in, const int* in_sizes, int n_in,
                              void* d_out, int out_size, void* d_ws, size_t ws_size,
                              hipStream_t stream) {
    const float* x  = (const float*)d_in[0];
    const int*   ei = (const int*)d_in[1];   // [2, E] int32
    const float* W1 = (const float*)d_in[2]; // [128, 64]
    const float* b1 = (const float*)d_in[3]; // [64]
    const float* W2 = (const float*)d_in[4]; // [64, 40]
    const float* b2 = (const float*)d_in[5]; // [40]
    float* out = (float*)d_out;              // [n, 40]

    const int n = in_sizes[0] / 128;
    const int e = in_sizes[1] / 2;
    const int* src = ei;
    const int* dst = ei + e;
    const int nb = (n + 511) >> BSHIFT;      // buckets of 512 nodes, <= 256

    // workspace layout (~54 MB):
    //   gcount[256] i32 | cnt[n] i32 | dis[n] f32 |
    //   bucketbuf[nb*BCAP] int2  (overlaid after csrify: A[n*64] bf16, then z_pre[n*40] bf16)
    //   srcs2d[n*64] i32 | B[n*64] bf16
    int* gcount = (int*)d_ws;
    int* cnt    = gcount + 256;
    float* dis  = (float*)(cnt + n);
    int2* bucketbuf = (int2*)(dis + n);
    u16* A      = (u16*)bucketbuf;           // n*64*2 B <= nb*BCAP*8 B
    int* srcs2d = (int*)(bucketbuf + (size_t)nb * BCAP);
    u16* B      = (u16*)(srcs2d + ((size_t)n << 6));

    const int T = 256;

    // --- adjacency build (bucket sort, no per-edge global atomics) ---
    zero_gcount_kernel<<<1, 256, 0, stream>>>(gcount);
    bucket_kernel<<<448, 256, 0, stream>>>(src, dst, gcount, bucketbuf, e, nb);
    csrify_kernel<<<nb, 256, 0, stream>>>(bucketbuf, gcount, cnt, dis, srcs2d, n);

    // --- layer 1: xw1 = x@W1 (bf16, into A over dead bucketbuf) ; H = relu(agg + b1) ---
    gemm_tile_kernel<float, u16, 128, 64, false>
        <<<(n + 63) / 64, 256, 0, stream>>>(x, W1, nullptr, A, n);
    gather64_kernel<<<(n * 64 + T - 1) / T, T, 0, stream>>>(A, cnt, srcs2d, dis, b1, B, n);

    // --- layer 2: z_pre = H@W2 (bf16, no bias) ; out = log_softmax(agg(z_pre) + b2) ---
    gemm_tile_kernel<u16, u16, 64, 40, false>
        <<<(n + 63) / 64, 256, 0, stream>>>(B, W2, nullptr, A, n);
    gather40_kernel<<<(n * 64 + T - 1) / T, T, 0, stream>>>(A, cnt, srcs2d, dis, b2, out, n);
}

// Round 9
// 347.553 us; speedup vs baseline: 1.3493x; 1.0548x over previous
//
#include <hip/hip_runtime.h>
#include <math.h>

typedef unsigned short u16;
typedef unsigned int u32;

#define CAP 64      // max in-degree stored per node (Poisson(16): P(>64) ~ 1e-20)
#define BSHIFT 9    // 512 nodes per bucket -> nb = ceil(n/512) <= 256 for n <= 131072
#define BCAP 9600   // records per bucket region (mean 8163 -> 16 sigma headroom)

// bf16 <-> f32 (bf16 = truncated f32; up-convert is an exact shift)
__device__ inline float bf2f(u16 u) {
    union { u32 i; float f; } c; c.i = ((u32)u) << 16; return c.f;
}
__device__ inline u16 f2bf(float f) {  // round-to-nearest-even
    union { float f; u32 i; } c; c.f = f;
    u32 r = c.i + 0x7FFFu + ((c.i >> 16) & 1u);
    return (u16)(r >> 16);
}

// ---------------- adjacency build: two-pass LDS bucket sort ----------------
// (round-7 post-mortem: device-scope atomics resolve at the memory-side
// coherence point -> per-edge random global atomics were the bottleneck;
// bucket sort replaces them with per-(block,bucket) reservations.)

__global__ void zero_gcount_kernel(int* __restrict__ gcount) {
    gcount[threadIdx.x] = 0;
}

__global__ __launch_bounds__(256) void bucket_kernel(const int* __restrict__ src,
                                                     const int* __restrict__ dst,
                                                     int* __restrict__ gcount,
                                                     int2* __restrict__ bucketbuf,
                                                     int e, int nb) {
    __shared__ int lh[256];
    int tid = threadIdx.x;
    if (tid < nb) lh[tid] = 0;
    __syncthreads();
    int per = (e + gridDim.x - 1) / gridDim.x;
    int i0 = blockIdx.x * per;
    int i1 = i0 + per; if (i1 > e) i1 = e;
    for (int i = i0 + tid; i < i1; i += 256)
        atomicAdd(&lh[dst[i] >> BSHIFT], 1);
    __syncthreads();
    if (tid < nb) {
        int c = lh[tid];
        lh[tid] = (c > 0) ? atomicAdd(&gcount[tid], c) : 0;
    }
    __syncthreads();
    for (int i = i0 + tid; i < i1; i += 256) {
        int d = dst[i], s = src[i];
        int b = d >> BSHIFT;
        int pos = atomicAdd(&lh[b], 1);  // LDS cursor -> unique global slot
        if (pos < BCAP) bucketbuf[(size_t)b * BCAP + pos] = make_int2(d, s);
    }
}

__global__ __launch_bounds__(256) void csrify_kernel(const int2* __restrict__ bucketbuf,
                                                     const int* __restrict__ gcount,
                                                     int* __restrict__ cnt,
                                                     float* __restrict__ dis,
                                                     int* __restrict__ srcs2d, int n) {
    __shared__ int lc[512];
    int b = blockIdx.x;
    int tid = threadIdx.x;
    int node_lo = b << BSHIFT;
    #pragma unroll
    for (int q = tid; q < 512; q += 256) lc[q] = 0;
    __syncthreads();
    int m = gcount[b]; if (m > BCAP) m = BCAP;
    const int2* bp = bucketbuf + (size_t)b * BCAP;
    for (int i = tid; i < m; i += 256) {
        int2 r = bp[i];
        int k = atomicAdd(&lc[r.x - node_lo], 1);
        if (k < CAP) srcs2d[((size_t)r.x << 6) + k] = r.y;
    }
    __syncthreads();
    for (int q = tid; q < 512; q += 256) {
        int node = node_lo + q;
        if (node < n) {
            int c = lc[q];
            cnt[node] = c;
            dis[node] = rsqrtf((float)c + 1.0f);
        }
    }
}

// ---------------- register-tiled GEMM: Y[n,OUT] = dis[r] * (X[n,IN] @ W[IN,OUT]) ----------------
// block = 256 threads -> 64 rows x 64 (padded) cols; thread = 4x4 tile.
// k-loop kept at unroll 1 (round-3 post-mortem: full unroll -> 256 VGPR spill).
// SCALE: epilogue multiplies row r by dis[r] (source-side GCN normalization folded
// in so the gathers become pure row sums — round-8 post-mortem: per-edge dis[s]
// loads + weight muls were a large share of gather VALU/latency).

__device__ inline float4 load4(const float* p) { return *(const float4*)p; }
__device__ inline float4 load4(const u16* p) {
    ushort4 u = *(const ushort4*)p;
    return make_float4(bf2f(u.x), bf2f(u.y), bf2f(u.z), bf2f(u.w));
}

template<typename XT, int IN_F, int OUT_F>
__global__ __launch_bounds__(256) void gemm_scale_kernel(const XT* __restrict__ X,
                                                         const float* __restrict__ W,
                                                         const float* __restrict__ dis,
                                                         u16* __restrict__ Y, int n) {
    constexpr int PC = 64;  // padded col count
    __shared__ float Wl[IN_F * PC];
    int tid = threadIdx.x;
    for (int idx = tid; idx < IN_F * PC; idx += 256) {
        int k = idx / PC, c = idx % PC;
        Wl[idx] = (c < OUT_F) ? W[k * OUT_F + c] : 0.f;
    }
    __syncthreads();
    int tx = tid & 15;   // col group (4 cols)
    int ty = tid >> 4;   // row group (4 rows)
    int r0 = blockIdx.x * 64 + ty * 4;
    int c0 = tx * 4;
    const XT* xr[4];
    #pragma unroll
    for (int i = 0; i < 4; ++i) {
        int r = r0 + i;
        if (r >= n) r = n - 1;
        xr[i] = X + (size_t)r * IN_F;
    }
    float acc[4][4] = {};
    const float4* Wv = (const float4*)Wl;  // index: k*16 + tx
    #pragma unroll 1
    for (int k = 0; k < IN_F; k += 4) {
        float4 xv[4];
        #pragma unroll
        for (int i = 0; i < 4; ++i) xv[i] = load4(xr[i] + k);
        #pragma unroll
        for (int j = 0; j < 4; ++j) {
            float4 wv = Wv[(k + j) * 16 + tx];
            #pragma unroll
            for (int i = 0; i < 4; ++i) {
                float xs = (j == 0) ? xv[i].x : (j == 1) ? xv[i].y : (j == 2) ? xv[i].z : xv[i].w;
                acc[i][0] = fmaf(xs, wv.x, acc[i][0]);
                acc[i][1] = fmaf(xs, wv.y, acc[i][1]);
                acc[i][2] = fmaf(xs, wv.z, acc[i][2]);
                acc[i][3] = fmaf(xs, wv.w, acc[i][3]);
            }
        }
    }
    if (c0 < OUT_F) {
        #pragma unroll
        for (int i = 0; i < 4; ++i) {
            int r = r0 + i;
            if (r < n) {
                float sc = dis[r];
                ushort4 o;
                o.x = f2bf(acc[i][0] * sc);
                o.y = f2bf(acc[i][1] * sc);
                o.z = f2bf(acc[i][2] * sc);
                o.w = f2bf(acc[i][3] * sc);
                *(ushort4*)(Y + (size_t)r * OUT_F + c0) = o;
            }
        }
    }
}

// ---------------- gather aggregation (one 64-lane wave per node) ----------------
// Input rows are pre-scaled by dis[src]; gather is a pure row-sum:
//   H[i,c] = relu( di * (v[i,c] + sum_k v[s_k,c]) + b[c] )
// unroll 16 for deep MLP on the random row gathers (deg mean ~16).

__global__ void gather64_kernel(const u16* __restrict__ v, const int* __restrict__ cnt,
                                const int* __restrict__ srcs2d, const float* __restrict__ dis,
                                const float* __restrict__ b, u16* __restrict__ out, int n) {
    int wid = __builtin_amdgcn_readfirstlane((blockIdx.x * blockDim.x + threadIdx.x) >> 6);
    int lane = threadIdx.x & 63;
    if (wid >= n) return;  // wave-uniform
    int deg = __builtin_amdgcn_readfirstlane(cnt[wid]);
    if (deg > CAP) deg = CAP;
    const int* sp = srcs2d + ((size_t)wid << 6);
    float di = dis[wid];
    float acc = bf2f(v[((size_t)wid << 6) + lane]);
    int k = 0;
    for (; k + 16 <= deg; k += 16) {
        int s[16];
        #pragma unroll
        for (int q = 0; q < 16; ++q) s[q] = sp[k + q];
        float vv[16];
        #pragma unroll
        for (int q = 0; q < 16; ++q) vv[q] = bf2f(v[((size_t)s[q] << 6) + lane]);
        #pragma unroll
        for (int q = 0; q < 16; ++q) acc += vv[q];
    }
    for (; k + 8 <= deg; k += 8) {
        int s[8];
        #pragma unroll
        for (int q = 0; q < 8; ++q) s[q] = sp[k + q];
        float vv[8];
        #pragma unroll
        for (int q = 0; q < 8; ++q) vv[q] = bf2f(v[((size_t)s[q] << 6) + lane]);
        #pragma unroll
        for (int q = 0; q < 8; ++q) acc += vv[q];
    }
    for (; k < deg; ++k) acc += bf2f(v[((size_t)sp[k] << 6) + lane]);
    acc = fmaxf(fmaf(di, acc, b[lane]), 0.f);
    out[((size_t)wid << 6) + lane] = f2bf(acc);
}

// 40-col row-sum gather + bias + log_softmax (one wave per node):
//   out[i,:] = log_softmax( di * (z[i,:] + sum_k z[s_k,:]) + b2 )
__global__ void gather40_kernel(const u16* __restrict__ z, const int* __restrict__ cnt,
                                const int* __restrict__ srcs2d, const float* __restrict__ dis,
                                const float* __restrict__ b2, float* __restrict__ out, int n) {
    int wid = __builtin_amdgcn_readfirstlane((blockIdx.x * blockDim.x + threadIdx.x) >> 6);
    int lane = threadIdx.x & 63;
    if (wid >= n) return;  // wave-uniform
    int deg = __builtin_amdgcn_readfirstlane(cnt[wid]);
    if (deg > CAP) deg = CAP;
    const int* sp = srcs2d + ((size_t)wid << 6);
    float di = dis[wid];
    bool act = lane < 40;
    float acc = act ? bf2f(z[(size_t)wid * 40 + lane]) : 0.f;
    int k = 0;
    for (; k + 16 <= deg; k += 16) {
        int s[16];
        #pragma unroll
        for (int q = 0; q < 16; ++q) s[q] = sp[k + q];
        float vv[16];
        #pragma unroll
        for (int q = 0; q < 16; ++q) vv[q] = act ? bf2f(z[(size_t)s[q] * 40 + lane]) : 0.f;
        #pragma unroll
        for (int q = 0; q < 16; ++q) acc += vv[q];
    }
    for (; k + 8 <= deg; k += 8) {
        int s[8];
        #pragma unroll
        for (int q = 0; q < 8; ++q) s[q] = sp[k + q];
        float vv[8];
        #pragma unroll
        for (int q = 0; q < 8; ++q) vv[q] = act ? bf2f(z[(size_t)s[q] * 40 + lane]) : 0.f;
        #pragma unroll
        for (int q = 0; q < 8; ++q) acc += vv[q];
    }
    for (; k < deg; ++k) {
        if (act) acc += bf2f(z[(size_t)sp[k] * 40 + lane]);
    }
    // fused bias + log_softmax over lanes 0..39
    float zz = act ? fmaf(di, acc, b2[lane]) : -INFINITY;
    float v = zz;
    #pragma unroll
    for (int off = 32; off > 0; off >>= 1) v = fmaxf(v, __shfl_xor(v, off));
    float ex = act ? expf(zz - v) : 0.f;
    float ss = ex;
    #pragma unroll
    for (int off = 32; off > 0; off >>= 1) ss += __shfl_xor(ss, off);
    float ls = logf(ss);
    if (act) out[(size_t)wid * 40 + lane] = zz - v - ls;
}

// ---------------- launch ----------------

extern "C" void kernel_launch(void* const* d_in, const int* in_sizes, int n_in,
                              void* d_out, int out_size, void* d_ws, size_t ws_size,
                              hipStream_t stream) {
    const float* x  = (const float*)d_in[0];
    const int*   ei = (const int*)d_in[1];   // [2, E] int32
    const float* W1 = (const float*)d_in[2]; // [128, 64]
    const float* b1 = (const float*)d_in[3]; // [64]
    const float* W2 = (const float*)d_in[4]; // [64, 40]
    const float* b2 = (const float*)d_in[5]; // [40]
    float* out = (float*)d_out;              // [n, 40]

    const int n = in_sizes[0] / 128;
    const int e = in_sizes[1] / 2;
    const int* src = ei;
    const int* dst = ei + e;
    const int nb = (n + 511) >> BSHIFT;      // buckets of 512 nodes, <= 256

    // workspace layout (~54 MB):
    //   gcount[256] i32 | cnt[n] i32 | dis[n] f32 |
    //   bucketbuf[nb*BCAP] int2 (overlaid after csrify: A = scaled xw1 bf16 n*64,
    //                            then Z_scaled bf16 n*40)
    //   srcs2d[n*64] i32 | B[n*64] bf16 (H)
    int* gcount = (int*)d_ws;
    int* cnt    = gcount + 256;
    float* dis  = (float*)(cnt + n);
    int2* bucketbuf = (int2*)(dis + n);
    u16* A      = (u16*)bucketbuf;           // n*64*2 B <= nb*BCAP*8 B
    int* srcs2d = (int*)(bucketbuf + (size_t)nb * BCAP);
    u16* B      = (u16*)(srcs2d + ((size_t)n << 6));

    const int T = 256;

    // --- adjacency build (bucket sort, no per-edge global atomics) ---
    zero_gcount_kernel<<<1, 256, 0, stream>>>(gcount);
    bucket_kernel<<<448, 256, 0, stream>>>(src, dst, gcount, bucketbuf, e, nb);
    csrify_kernel<<<nb, 256, 0, stream>>>(bucketbuf, gcount, cnt, dis, srcs2d, n);

    // --- layer 1: A = dis .* (x@W1) (bf16) ; H = relu(di * rowsum + b1) (bf16) ---
    gemm_scale_kernel<float, 128, 64>
        <<<(n + 63) / 64, 256, 0, stream>>>(x, W1, dis, A, n);
    gather64_kernel<<<(n * 64 + T - 1) / T, T, 0, stream>>>(A, cnt, srcs2d, dis, b1, B, n);

    // --- layer 2: Z = dis .* (H@W2) (bf16) ; out = log_softmax(di * rowsum + b2) ---
    gemm_scale_kernel<u16, 64, 40>
        <<<(n + 63) / 64, 256, 0, stream>>>(B, W2, dis, A, n);
    gather40_kernel<<<(n * 64 + T - 1) / T, T, 0, stream>>>(A, cnt, srcs2d, dis, b2, out, n);
}

// Round 10
// 295.351 us; speedup vs baseline: 1.5878x; 1.1767x over previous
//
#include <hip/hip_runtime.h>
#include <math.h>

typedef unsigned short u16;
typedef unsigned int u32;

#define CAP 64      // max in-degree stored per node (Poisson(16): P(>64) ~ 1e-20)
#define BSHIFT 9    // 512 nodes per bucket -> nb = ceil(n/512) <= 256 for n <= 131072
#define BCAP 9600   // records per bucket region (mean 8163 -> 16 sigma headroom)

// bf16 <-> f32 helpers
__device__ inline float bf2f(u16 u) {
    union { u32 i; float f; } c; c.i = ((u32)u) << 16; return c.f;
}
__device__ inline u16 f2bf(float f) {  // round-to-nearest-even
    union { float f; u32 i; } c; c.f = f;
    u32 r = c.i + 0x7FFFu + ((c.i >> 16) & 1u);
    return (u16)(r >> 16);
}
__device__ inline float bflo(u32 d) {  // low bf16 of a dword -> f32
    union { u32 i; float f; } c; c.i = d << 16; return c.f;
}
__device__ inline float bfhi(u32 d) {  // high bf16 of a dword -> f32
    union { u32 i; float f; } c; c.i = d & 0xFFFF0000u; return c.f;
}
__device__ inline u32 pack2(float lo, float hi) {
    return (u32)f2bf(lo) | ((u32)f2bf(hi) << 16);
}

// ---------------- adjacency build: two-pass LDS bucket sort ----------------
// (round-7 post-mortem: device-scope atomics resolve at the memory-side
// coherence point -> per-edge random global atomics were the bottleneck;
// bucket sort replaces them with per-(block,bucket) reservations.)

__global__ void zero_gcount_kernel(int* __restrict__ gcount) {
    gcount[threadIdx.x] = 0;
}

__global__ __launch_bounds__(256) void bucket_kernel(const int* __restrict__ src,
                                                     const int* __restrict__ dst,
                                                     int* __restrict__ gcount,
                                                     int2* __restrict__ bucketbuf,
                                                     int e, int nb) {
    __shared__ int lh[256];
    int tid = threadIdx.x;
    if (tid < nb) lh[tid] = 0;
    __syncthreads();
    int per = (e + gridDim.x - 1) / gridDim.x;
    int i0 = blockIdx.x * per;
    int i1 = i0 + per; if (i1 > e) i1 = e;
    for (int i = i0 + tid; i < i1; i += 256)
        atomicAdd(&lh[dst[i] >> BSHIFT], 1);
    __syncthreads();
    if (tid < nb) {
        int c = lh[tid];
        lh[tid] = (c > 0) ? atomicAdd(&gcount[tid], c) : 0;
    }
    __syncthreads();
    for (int i = i0 + tid; i < i1; i += 256) {
        int d = dst[i], s = src[i];
        int b = d >> BSHIFT;
        int pos = atomicAdd(&lh[b], 1);  // LDS cursor -> unique global slot
        if (pos < BCAP) bucketbuf[(size_t)b * BCAP + pos] = make_int2(d, s);
    }
}

__global__ __launch_bounds__(256) void csrify_kernel(const int2* __restrict__ bucketbuf,
                                                     const int* __restrict__ gcount,
                                                     int* __restrict__ cnt,
                                                     float* __restrict__ dis,
                                                     int* __restrict__ srcs2d, int n) {
    __shared__ int lc[512];
    int b = blockIdx.x;
    int tid = threadIdx.x;
    int node_lo = b << BSHIFT;
    #pragma unroll
    for (int q = tid; q < 512; q += 256) lc[q] = 0;
    __syncthreads();
    int m = gcount[b]; if (m > BCAP) m = BCAP;
    const int2* bp = bucketbuf + (size_t)b * BCAP;
    for (int i = tid; i < m; i += 256) {
        int2 r = bp[i];
        int k = atomicAdd(&lc[r.x - node_lo], 1);
        if (k < CAP) srcs2d[((size_t)r.x << 6) + k] = r.y;
    }
    __syncthreads();
    for (int q = tid; q < 512; q += 256) {
        int node = node_lo + q;
        if (node < n) {
            int c = lc[q];
            cnt[node] = c;
            dis[node] = rsqrtf((float)c + 1.0f);
        }
    }
}

// ---------------- register-tiled GEMM: Y[n, OSTR] = dis[r] * (X[n,IN] @ W[IN,OUT]) ----------------
// block = 256 threads -> 64 rows x 64 (padded) cols; thread = 4x4 tile.
// k-loop kept at unroll 1 (round-3 post-mortem: full unroll -> 256 VGPR spill).
// Epilogue scales row r by dis[r] (source-side GCN normalization folded in).
// Cols OUT_F..OSTR-1 are written as exact zeros (W staged zero-padded).

__device__ inline float4 load4(const float* p) { return *(const float4*)p; }
__device__ inline float4 load4(const u16* p) {
    ushort4 u = *(const ushort4*)p;
    return make_float4(bf2f(u.x), bf2f(u.y), bf2f(u.z), bf2f(u.w));
}

template<typename XT, int IN_F, int OUT_F, int OSTR>
__global__ __launch_bounds__(256) void gemm_scale_kernel(const XT* __restrict__ X,
                                                         const float* __restrict__ W,
                                                         const float* __restrict__ dis,
                                                         u16* __restrict__ Y, int n) {
    constexpr int PC = 64;  // padded col count (== OSTR)
    __shared__ float Wl[IN_F * PC];
    int tid = threadIdx.x;
    for (int idx = tid; idx < IN_F * PC; idx += 256) {
        int k = idx / PC, c = idx % PC;
        Wl[idx] = (c < OUT_F) ? W[k * OUT_F + c] : 0.f;
    }
    __syncthreads();
    int tx = tid & 15;   // col group (4 cols)
    int ty = tid >> 4;   // row group (4 rows)
    int r0 = blockIdx.x * 64 + ty * 4;
    int c0 = tx * 4;
    const XT* xr[4];
    #pragma unroll
    for (int i = 0; i < 4; ++i) {
        int r = r0 + i;
        if (r >= n) r = n - 1;
        xr[i] = X + (size_t)r * IN_F;
    }
    float acc[4][4] = {};
    const float4* Wv = (const float4*)Wl;  // index: k*16 + tx
    #pragma unroll 1
    for (int k = 0; k < IN_F; k += 4) {
        float4 xv[4];
        #pragma unroll
        for (int i = 0; i < 4; ++i) xv[i] = load4(xr[i] + k);
        #pragma unroll
        for (int j = 0; j < 4; ++j) {
            float4 wv = Wv[(k + j) * 16 + tx];
            #pragma unroll
            for (int i = 0; i < 4; ++i) {
                float xs = (j == 0) ? xv[i].x : (j == 1) ? xv[i].y : (j == 2) ? xv[i].z : xv[i].w;
                acc[i][0] = fmaf(xs, wv.x, acc[i][0]);
                acc[i][1] = fmaf(xs, wv.y, acc[i][1]);
                acc[i][2] = fmaf(xs, wv.z, acc[i][2]);
                acc[i][3] = fmaf(xs, wv.w, acc[i][3]);
            }
        }
    }
    #pragma unroll
    for (int i = 0; i < 4; ++i) {
        int r = r0 + i;
        if (r < n) {
            float sc = dis[r];
            ushort4 o;
            o.x = f2bf(acc[i][0] * sc);
            o.y = f2bf(acc[i][1] * sc);
            o.z = f2bf(acc[i][2] * sc);
            o.w = f2bf(acc[i][3] * sc);
            *(ushort4*)(Y + (size_t)r * OSTR + c0) = o;
        }
    }
}

// ---------------- wide-load gather: one wave per node, 8 rows per load instr ----------------
// Round-9 post-mortem: gathers are vector-mem INSTRUCTION bound (~34 cyc/instr,
// VALUBusy 24%, BW 15%), not byte bound. Fix: lane = (j<<3)|c; j = row-in-batch
// (8 rows), c = col-group (8 bf16 = 16 B). One dwordx4 load fetches 8 neighbor
// rows; indices come from one 256 B adjacency load + one ds_bpermute per batch;
// j-reduction via 3 shfl_xor steps. ~5 vector-mem instrs/node vs ~19 before.
// Input rows pre-scaled by dis[src]; both layers use 64-col (128 B) rows.
//   FINAL=0: H[i,:] = relu(di * rowsum + b)        -> bf16, 64 cols
//   FINAL=1: out[i,:] = log_softmax(di*rowsum + b) -> f32, first 40 cols

template<int FINAL>
__global__ __launch_bounds__(256) void gatherw_kernel(const u16* __restrict__ v,
                                                      const int* __restrict__ cnt,
                                                      const int* __restrict__ srcs2d,
                                                      const float* __restrict__ dis,
                                                      const float* __restrict__ bias,
                                                      u16* __restrict__ outb,
                                                      float* __restrict__ outf, int n) {
    int wid = __builtin_amdgcn_readfirstlane((blockIdx.x * blockDim.x + threadIdx.x) >> 6);
    int lane = threadIdx.x & 63;
    if (wid >= n) return;  // wave-uniform
    int deg = __builtin_amdgcn_readfirstlane(cnt[wid]);
    if (deg > CAP) deg = CAP;
    int nrows = deg + 1;                       // virtual row list: [self, neighbors...]
    int j = lane >> 3;                         // row within batch (0..7)
    int c = lane & 7;                          // col-group (8 bf16 each)
    int idx_all = srcs2d[((size_t)wid << 6) + lane];  // whole adjacency row, 256 B
    float acc[8] = {};
    for (int k = 0; k < nrows; k += 8) {
        int pos = k + j;
        int sj = __shfl(idx_all, (pos - 1) & 63);
        sj = (pos == 0) ? wid : sj;
        bool val = pos < nrows;
        sj = val ? sj : wid;                   // safe address for masked rows
        float m = val ? 1.f : 0.f;
        const uint4* rp = (const uint4*)(v + (((size_t)sj) << 6) + (c << 3));
        uint4 a = *rp;                         // 16 B = 8 bf16 of row sj
        acc[0] = fmaf(bflo(a.x), m, acc[0]);
        acc[1] = fmaf(bfhi(a.x), m, acc[1]);
        acc[2] = fmaf(bflo(a.y), m, acc[2]);
        acc[3] = fmaf(bfhi(a.y), m, acc[3]);
        acc[4] = fmaf(bflo(a.z), m, acc[4]);
        acc[5] = fmaf(bfhi(a.z), m, acc[5]);
        acc[6] = fmaf(bflo(a.w), m, acc[6]);
        acc[7] = fmaf(bfhi(a.w), m, acc[7]);
    }
    #pragma unroll
    for (int i = 0; i < 8; ++i) {              // reduce over j (all lanes end with totals)
        acc[i] += __shfl_xor(acc[i], 8);
        acc[i] += __shfl_xor(acc[i], 16);
        acc[i] += __shfl_xor(acc[i], 32);
    }
    float di = dis[wid];
    if (FINAL == 0) {
        float4 b0 = *(const float4*)(bias + (c << 3));
        float4 b1 = *(const float4*)(bias + (c << 3) + 4);
        float o0 = fmaxf(fmaf(di, acc[0], b0.x), 0.f);
        float o1 = fmaxf(fmaf(di, acc[1], b0.y), 0.f);
        float o2 = fmaxf(fmaf(di, acc[2], b0.z), 0.f);
        float o3 = fmaxf(fmaf(di, acc[3], b0.w), 0.f);
        float o4 = fmaxf(fmaf(di, acc[4], b1.x), 0.f);
        float o5 = fmaxf(fmaf(di, acc[5], b1.y), 0.f);
        float o6 = fmaxf(fmaf(di, acc[6], b1.z), 0.f);
        float o7 = fmaxf(fmaf(di, acc[7], b1.w), 0.f);
        if (j == 0) {
            uint4 p = make_uint4(pack2(o0, o1), pack2(o2, o3), pack2(o4, o5), pack2(o6, o7));
            *(uint4*)(outb + (((size_t)wid) << 6) + (c << 3)) = p;
        }
    } else {
        bool act = c < 5;                      // col-groups 0..4 = cols 0..39
        int cb = act ? c : 0;
        float4 b0 = *(const float4*)(bias + (cb << 3));
        float4 b1 = *(const float4*)(bias + (cb << 3) + 4);
        float zz[8];
        zz[0] = act ? fmaf(di, acc[0], b0.x) : -INFINITY;
        zz[1] = act ? fmaf(di, acc[1], b0.y) : -INFINITY;
        zz[2] = act ? fmaf(di, acc[2], b0.z) : -INFINITY;
        zz[3] = act ? fmaf(di, acc[3], b0.w) : -INFINITY;
        zz[4] = act ? fmaf(di, acc[4], b1.x) : -INFINITY;
        zz[5] = act ? fmaf(di, acc[5], b1.y) : -INFINITY;
        zz[6] = act ? fmaf(di, acc[6], b1.z) : -INFINITY;
        zz[7] = act ? fmaf(di, acc[7], b1.w) : -INFINITY;
        float mx = zz[0];
        #pragma unroll
        for (int i = 1; i < 8; ++i) mx = fmaxf(mx, zz[i]);
        mx = fmaxf(mx, __shfl_xor(mx, 1));
        mx = fmaxf(mx, __shfl_xor(mx, 2));
        mx = fmaxf(mx, __shfl_xor(mx, 4));
        float ssum = 0.f;
        if (act) {
            #pragma unroll
            for (int i = 0; i < 8; ++i) ssum += expf(zz[i] - mx);
        }
        ssum += __shfl_xor(ssum, 1);
        ssum += __shfl_xor(ssum, 2);
        ssum += __shfl_xor(ssum, 4);
        float ls = logf(ssum) + mx;
        if (j == 0 && act) {
            float* op = outf + (size_t)wid * 40 + (c << 3);
            *(float4*)op = make_float4(zz[0] - ls, zz[1] - ls, zz[2] - ls, zz[3] - ls);
            *(float4*)(op + 4) = make_float4(zz[4] - ls, zz[5] - ls, zz[6] - ls, zz[7] - ls);
        }
    }
}

// ---------------- launch ----------------

extern "C" void kernel_launch(void* const* d_in, const int* in_sizes, int n_in,
                              void* d_out, int out_size, void* d_ws, size_t ws_size,
                              hipStream_t stream) {
    const float* x  = (const float*)d_in[0];
    const int*   ei = (const int*)d_in[1];   // [2, E] int32
    const float* W1 = (const float*)d_in[2]; // [128, 64]
    const float* b1 = (const float*)d_in[3]; // [64]
    const float* W2 = (const float*)d_in[4]; // [64, 40]
    const float* b2 = (const float*)d_in[5]; // [40]
    float* out = (float*)d_out;              // [n, 40]

    const int n = in_sizes[0] / 128;
    const int e = in_sizes[1] / 2;
    const int* src = ei;
    const int* dst = ei + e;
    const int nb = (n + 511) >> BSHIFT;      // buckets of 512 nodes, <= 256

    // workspace layout (~54 MB):
    //   gcount[256] i32 | cnt[n] i32 | dis[n] f32 |
    //   bucketbuf[nb*BCAP] int2 (overlaid after csrify: A bf16 n*64 — xw1-scaled,
    //                            then Z-scaled 64-col padded)
    //   srcs2d[n*64] i32 | B[n*64] bf16 (H)
    int* gcount = (int*)d_ws;
    int* cnt    = gcount + 256;
    float* dis  = (float*)(cnt + n);
    int2* bucketbuf = (int2*)(dis + n);
    u16* A      = (u16*)bucketbuf;           // n*64*2 B <= nb*BCAP*8 B
    int* srcs2d = (int*)(bucketbuf + (size_t)nb * BCAP);
    u16* B      = (u16*)(srcs2d + ((size_t)n << 6));

    const int T = 256;
    const int gblocks = (n * 64 + T - 1) / T;

    // --- adjacency build (bucket sort, no per-edge global atomics) ---
    zero_gcount_kernel<<<1, 256, 0, stream>>>(gcount);
    bucket_kernel<<<448, 256, 0, stream>>>(src, dst, gcount, bucketbuf, e, nb);
    csrify_kernel<<<nb, 256, 0, stream>>>(bucketbuf, gcount, cnt, dis, srcs2d, n);

    // --- layer 1: A = dis .* (x@W1) (bf16, 64 cols) ; H = relu(di*rowsum + b1) ---
    gemm_scale_kernel<float, 128, 64, 64>
        <<<(n + 63) / 64, 256, 0, stream>>>(x, W1, dis, A, n);
    gatherw_kernel<0><<<gblocks, T, 0, stream>>>(A, cnt, srcs2d, dis, b1, B, nullptr, n);

    // --- layer 2: A = dis .* (H@W2) (bf16, 64-col padded, cols 40-63 = 0) ;
    //              out = log_softmax(di*rowsum + b2) ---
    gemm_scale_kernel<u16, 64, 40, 64>
        <<<(n + 63) / 64, 256, 0, stream>>>(B, W2, dis, A, n);
    gatherw_kernel<1><<<gblocks, T, 0, stream>>>(A, cnt, srcs2d, dis, b2, nullptr, out, n);
}